// Round 3
// baseline (986.347 us; speedup 1.0000x reference)
//
#include <hip/hip_runtime.h>
#include <hip/hip_fp16.h>

// Problem constants
#define NCLS 512
#define COUT 256
#define BB 4
#define TT 16
#define HH 64
#define WW 64

typedef float vfloat4 __attribute__((ext_vector_type(4)));   // builtin vec for nontemporal store

static constexpr size_t TABLE_ELEMS = 27ull * NCLS * COUT;   // half elements
static constexpr size_t TABLE_BYTES = TABLE_ELEMS * sizeof(__half);

// ---------------------------------------------------------------------------
// Kernel 1: repack weight (C=256, N=512, 27) fp32 -> table[27][512][256] half.
// Column j of a row holds original channel  c(j) = (j>>7)*128 + (j&7)*16 + ((j&127)>>3)
// (pass-half in bit 7; within-pass perm so a lane's dwordx4 in kernel 2 holds
// channels {l4, 16+l4, ..., 112+l4} -> conflict-free LDS transpose).
//
// LDS-tiled transpose: block = (pass, 4-n tile). Read side: 128 contiguous
// 432 B runs (c-major input), 2 threads/run -> every line fetched once and
// fully consumed (the old version issued 64-distinct-line divergent loads,
// ~3.5M cold line-misses ~= 250 us). Write side: 64 consecutive dwords per
// wave = 256 B coalesced rows.
// ---------------------------------------------------------------------------
#define RST 109   // LDS row stride (floats), odd -> spread banks

__global__ __launch_bounds__(256) void repack_kernel(const float* __restrict__ w,
                                                     __half* __restrict__ tbl) {
    __shared__ float s[128 * RST];        // [c_local][n*27+k], 55.8 KB

    int bid  = blockIdx.x;                // 0..255
    int pass = bid >> 7;                  // 0/1: channel half
    int n0   = (bid & 127) << 2;          // 4 consecutive n
    int tid  = threadIdx.x;

    // ---- read: c_local r owns 108 contiguous floats (4n x 27k), 2 threads/run
    {
        int r  = tid >> 1;                // 0..127
        int l2 = tid & 1;
        int cg = pass * 128 + r;          // global channel
        const float* src = w + ((size_t)cg * NCLS + n0) * 27;
#pragma unroll
        for (int i = 0; i < 54; ++i) {
            int f = l2 + (i << 1);        // 0..107
            s[r * RST + f] = src[f];
        }
    }
    __syncthreads();

    // ---- write: dword d = k*256 + tid covers (k, n = tid>>6, pd = tid&63);
    // halves (2pd, 2pd+1) hold channels c0, c0+16 with c0 = 32*(pd&3)+(pd>>2).
    unsigned int* tb32 = reinterpret_cast<unsigned int*>(tbl);
    int n  = tid >> 6;                    // 0..3
    int pd = tid & 63;                    // 0..63
    int c0 = ((pd & 3) << 5) + (pd >> 2);
    int q0 = n * 27;
#pragma unroll
    for (int k = 0; k < 27; ++k) {
        float a = s[c0 * RST + q0 + k];
        float b = s[(c0 + 16) * RST + q0 + k];
        __half2 hv = __floats2half2_rn(a, b);
        tb32[((size_t)k * NCLS + n0 + n) * 128 + pass * 64 + pd] =
            *reinterpret_cast<unsigned int*>(&hv);
    }
}

// ---------------------------------------------------------------------------
// Kernel 2: main gather-accumulate, 2-pass channel split pinned to XCD halves.
// 8192 blocks; with round-robin block->XCD dispatch, XCDs 0-3 get pass 0
// (channels 0-127), XCDs 4-7 pass 1. Per-XCD table working set = 3.5 MB
// -> resident in the 4 MB XCD L2 (was 7 MB -> 830 MB/iter L3 refill).
// Quarter-wave pairing: 16 lanes x 16 B = one 256 B half-row; 4 w per wave
// per load; 108 dwordx4 loads/thread issued in 9-deep batches.
// Output: nontemporal full-line stores (don't evict the table from L2).
// ---------------------------------------------------------------------------
__global__ __launch_bounds__(256, 4) void conv_kernel(const int* __restrict__ idx,
                                                      const __half* __restrict__ tbl,
                                                      const float* __restrict__ bias,
                                                      float* __restrict__ out) {
    __shared__ int soff[3 * 3 * 66];      // per-tap-row byte offsets (n << 9)
    __shared__ float tile[64 * 136];      // [w][c_local], padded stride, 34.8 KB

    int bx   = blockIdx.x;                // 0..8191
    int pass = (bx >> 2) & 1;             // XCD half -> channel half
    int pos  = ((bx & 3) << 10) | (bx >> 3);   // bijective -> 0..4095
    int h = pos & 63;
    int t = (pos >> 6) & 15;
    int b = pos >> 10;
    int tid = threadIdx.x;

    // ---- stage clamped row byte-offsets for the (3 dt)x(3 dh)x(66 w) window
    for (int e = tid; e < 594; e += 256) {
        int tt = e / 198;
        int r  = e - tt * 198;
        int hh = r / 66;
        int ww = r - hh * 66;
        int ts = t + tt - 2; if (ts < 0) ts = 0;                 // edge pad (2,0)
        int hs = h + hh - 1; if (hs < 0) hs = 0; if (hs > 63) hs = 63;
        int ws = ww - 1;     if (ws < 0) ws = 0; if (ws > 63) ws = 63;
        int n = idx[(((b * TT + ts) * HH) + hs) * WW + ws];
        soff[e] = n << 9;                                        // n * 512 bytes
    }
    __syncthreads();

    int lane = tid & 63;
    int wave = tid >> 6;
    int quad = lane >> 4;                 // which w of the 4-group
    int l4   = lane & 15;                 // 16 B column slot within half-row
    const char* tb = (const char*)tbl + pass * 256 + l4 * 16;

#pragma unroll
    for (int pr = 0; pr < 4; ++pr) {
        int w = (wave << 4) + (pr << 2) + quad;     // unique 0..63
        __half2 a0 = __float2half2_rn(0.0f);
        __half2 a1 = a0, a2 = a0, a3 = a0;
#pragma unroll
        for (int g = 0; g < 3; ++g) {               // 3 groups of 9 taps
            int no[9];
#pragma unroll
            for (int i = 0; i < 9; ++i) {
                int kt = g * 3 + i / 3;             // tap row (dt*3+dh)
                int dw = i % 3;
                no[i] = soff[kt * 66 + w + dw];
            }
            uint4 ld[9];
#pragma unroll
            for (int i = 0; i < 9; ++i) {
                int k = g * 9 + i;                  // tap 0..26
                ld[i] = *reinterpret_cast<const uint4*>(tb + (no[i] + k * 262144));
            }
#pragma unroll
            for (int i = 0; i < 9; ++i) {
                union { uint4 u; __half2 h2[4]; } v; v.u = ld[i];
                a0 = __hadd2(a0, v.h2[0]);
                a1 = __hadd2(a1, v.h2[1]);
                a2 = __hadd2(a2, v.h2[2]);
                a3 = __hadd2(a3, v.h2[3]);
            }
        }
        // half e of the dwordx4 is (within-pass) channel 16*e + l4:
        // tile stride 136 floats -> all 64 lanes hit distinct-bank pairs (free).
        float2 f0 = __half22float2(a0);
        float2 f1 = __half22float2(a1);
        float2 f2 = __half22float2(a2);
        float2 f3 = __half22float2(a3);
        float* tw = &tile[w * 136 + l4];
        tw[0]   = f0.x; tw[16]  = f0.y;
        tw[32]  = f1.x; tw[48]  = f1.y;
        tw[64]  = f2.x; tw[80]  = f2.y;
        tw[96]  = f3.x; tw[112] = f3.y;
    }
    __syncthreads();

    // ---- store phase: thread = (c_local, w-half); 32 contiguous w = one full
    // 128 B line per thread, written nontemporal.
    {
        int c    = tid & 127;
        int part = tid >> 7;
        float bv = bias[pass * 128 + c];
        float* obase = out + ((((size_t)b * COUT + pass * 128 + c) * TT + t) * HH + h) * WW
                           + part * 32;
#pragma unroll
        for (int j = 0; j < 8; ++j) {
            int w0 = part * 32 + j * 4;
            vfloat4 v;
            v.x = tile[(w0 + 0) * 136 + c] + bv;
            v.y = tile[(w0 + 1) * 136 + c] + bv;
            v.z = tile[(w0 + 2) * 136 + c] + bv;
            v.w = tile[(w0 + 3) * 136 + c] + bv;
            __builtin_nontemporal_store(v, reinterpret_cast<vfloat4*>(obase + j * 4));
        }
    }
}

// ---------------------------------------------------------------------------
// Fallback (only if workspace is too small for the half table): direct fp32
// gather from the original layout. Slow but correct.
// ---------------------------------------------------------------------------
__global__ __launch_bounds__(256) void conv_direct(const int* __restrict__ idx,
                                                   const float* __restrict__ wgt,
                                                   const float* __restrict__ bias,
                                                   float* __restrict__ out) {
    int bid = blockIdx.x;                 // b*65536 + t*4096 + h*64 + w
    int w = bid & 63;
    int h = (bid >> 6) & 63;
    int t = (bid >> 12) & 15;
    int b = bid >> 16;
    int c = threadIdx.x;
    float acc = bias[c];
#pragma unroll
    for (int dt = 0; dt < 3; ++dt)
#pragma unroll
        for (int dh = 0; dh < 3; ++dh)
#pragma unroll
            for (int dw = 0; dw < 3; ++dw) {
                int ts = t + dt - 2; if (ts < 0) ts = 0;
                int hs = h + dh - 1; if (hs < 0) hs = 0; if (hs > 63) hs = 63;
                int ws = w + dw - 1; if (ws < 0) ws = 0; if (ws > 63) ws = 63;
                int n = idx[(((b * TT + ts) * HH) + hs) * WW + ws];
                acc += wgt[((size_t)(c * NCLS + n)) * 27 + (dt * 9 + dh * 3 + dw)];
            }
    out[((((size_t)b * COUT + c) * TT + t) * HH + h) * WW + w] = acc;
}

extern "C" void kernel_launch(void* const* d_in, const int* in_sizes, int n_in,
                              void* d_out, int out_size, void* d_ws, size_t ws_size,
                              hipStream_t stream) {
    const int*   indices = (const int*)d_in[0];
    const float* weight  = (const float*)d_in[1];
    const float* bias    = (const float*)d_in[2];
    float*       out     = (float*)d_out;

    if (ws_size >= TABLE_BYTES) {
        __half* tbl = (__half*)d_ws;
        repack_kernel<<<256, 256, 0, stream>>>(weight, tbl);
        conv_kernel<<<2 * BB * TT * HH, 256, 0, stream>>>(indices, tbl, bias, out);
    } else {
        conv_direct<<<BB * TT * HH * WW, 256, 0, stream>>>(indices, weight, bias, out);
    }
}

// Round 4
// 449.907 us; speedup vs baseline: 2.1923x; 2.1923x over previous
//
#include <hip/hip_runtime.h>
#include <hip/hip_fp16.h>

// Problem constants
#define NCLS 512
#define COUT 256
#define BB 4
#define TT 16
#define HH 64
#define WW 64

static constexpr size_t TABLE_ELEMS = 27ull * NCLS * COUT;   // half elements
static constexpr size_t TABLE_BYTES = TABLE_ELEMS * sizeof(__half);

// ---------------------------------------------------------------------------
// Kernel 1: repack weight (C=256, N=512, 27) fp32 -> table[27][512][256] half.
// Column j of a row holds original channel  c(j) = (j>>7)*128 + (j&7)*16 + ((j&127)>>3)
// (pass-half in bit 7; within-pass perm so a lane's dwordx4 in kernel 2 holds
// channels {l4, 16+l4, ..., 112+l4} -> conflict-free LDS transpose).
// LDS-tiled transpose: coalesced-ish reads (each 432 B run fetched once,
// L1-consumed), fully-coalesced writes.
// ---------------------------------------------------------------------------
#define RST 109   // LDS row stride (floats), odd -> spread banks

__global__ __launch_bounds__(256) void repack_kernel(const float* __restrict__ w,
                                                     __half* __restrict__ tbl) {
    __shared__ float s[128 * RST];        // [c_local][n*27+k], 55.8 KB

    int bid  = blockIdx.x;                // 0..255
    int pass = bid >> 7;                  // 0/1: channel half
    int n0   = (bid & 127) << 2;          // 4 consecutive n
    int tid  = threadIdx.x;

    // ---- read: c_local r owns 108 contiguous floats (4n x 27k), 2 threads/run
    {
        int r  = tid >> 1;                // 0..127
        int l2 = tid & 1;
        int cg = pass * 128 + r;          // global channel
        const float* src = w + ((size_t)cg * NCLS + n0) * 27;
#pragma unroll
        for (int i = 0; i < 54; ++i) {
            int f = l2 + (i << 1);        // 0..107
            s[r * RST + f] = src[f];
        }
    }
    __syncthreads();

    // ---- write: dword d = k*256 + tid covers (k, n = tid>>6, pd = tid&63);
    // halves (2pd, 2pd+1) hold channels c0, c0+16 with c0 = 32*(pd&3)+(pd>>2).
    unsigned int* tb32 = reinterpret_cast<unsigned int*>(tbl);
    int n  = tid >> 6;                    // 0..3
    int pd = tid & 63;                    // 0..63
    int c0 = ((pd & 3) << 5) + (pd >> 2);
    int q0 = n * 27;
#pragma unroll
    for (int k = 0; k < 27; ++k) {
        float a = s[c0 * RST + q0 + k];
        float b = s[(c0 + 16) * RST + q0 + k];
        __half2 hv = __floats2half2_rn(a, b);
        tb32[((size_t)k * NCLS + n0 + n) * 128 + pass * 64 + pd] =
            *reinterpret_cast<unsigned int*>(&hv);
    }
}

// ---------------------------------------------------------------------------
// Kernel 2: main gather-accumulate, 2-pass channel split pinned to XCD halves.
// 8192 blocks; round-robin block->XCD dispatch puts pass 0 (channels 0-127)
// on XCDs 0-3 and pass 1 on XCDs 4-7. Per-XCD table working set = 3.5 MB ->
// resident in the 4 MB XCD L2 (verified: FETCH_SIZE 830 MB -> 35 MB).
// Quarter-wave pairing: 16 lanes x 16 B = one 256 B half-row; 4 w per wave
// per load; 108 dwordx4 loads/thread issued in 9-deep batches.
// Output: REGULAR cached float4 stores (NT stores caused 4x sector-write
// amplification: WRITE_SIZE 266 MB -> 1.05 GB, conv 291 -> 766 us).
// ---------------------------------------------------------------------------
__global__ __launch_bounds__(256, 4) void conv_kernel(const int* __restrict__ idx,
                                                      const __half* __restrict__ tbl,
                                                      const float* __restrict__ bias,
                                                      float* __restrict__ out) {
    __shared__ int soff[3 * 3 * 66];      // per-tap-row byte offsets (n << 9)
    __shared__ float tile[64 * 136];      // [w][c_local], padded stride, 34.8 KB

    int bx   = blockIdx.x;                // 0..8191
    int pass = (bx >> 2) & 1;             // XCD half -> channel half
    int pos  = ((bx & 3) << 10) | (bx >> 3);   // bijective -> 0..4095
    int h = pos & 63;
    int t = (pos >> 6) & 15;
    int b = pos >> 10;
    int tid = threadIdx.x;

    // ---- stage clamped row byte-offsets for the (3 dt)x(3 dh)x(66 w) window
    for (int e = tid; e < 594; e += 256) {
        int tt = e / 198;
        int r  = e - tt * 198;
        int hh = r / 66;
        int ww = r - hh * 66;
        int ts = t + tt - 2; if (ts < 0) ts = 0;                 // edge pad (2,0)
        int hs = h + hh - 1; if (hs < 0) hs = 0; if (hs > 63) hs = 63;
        int ws = ww - 1;     if (ws < 0) ws = 0; if (ws > 63) ws = 63;
        int n = idx[(((b * TT + ts) * HH) + hs) * WW + ws];
        soff[e] = n << 9;                                        // n * 512 bytes
    }
    __syncthreads();

    int lane = tid & 63;
    int wave = tid >> 6;
    int quad = lane >> 4;                 // which w of the 4-group
    int l4   = lane & 15;                 // 16 B column slot within half-row
    const char* tb = (const char*)tbl + pass * 256 + l4 * 16;

#pragma unroll
    for (int pr = 0; pr < 4; ++pr) {
        int w = (wave << 4) + (pr << 2) + quad;     // unique 0..63
        __half2 a0 = __float2half2_rn(0.0f);
        __half2 a1 = a0, a2 = a0, a3 = a0;
#pragma unroll
        for (int g = 0; g < 3; ++g) {               // 3 groups of 9 taps
            int no[9];
#pragma unroll
            for (int i = 0; i < 9; ++i) {
                int kt = g * 3 + i / 3;             // tap row (dt*3+dh)
                int dw = i % 3;
                no[i] = soff[kt * 66 + w + dw];
            }
            uint4 ld[9];
#pragma unroll
            for (int i = 0; i < 9; ++i) {
                int k = g * 9 + i;                  // tap 0..26
                ld[i] = *reinterpret_cast<const uint4*>(tb + (no[i] + k * 262144));
            }
#pragma unroll
            for (int i = 0; i < 9; ++i) {
                union { uint4 u; __half2 h2[4]; } v; v.u = ld[i];
                a0 = __hadd2(a0, v.h2[0]);
                a1 = __hadd2(a1, v.h2[1]);
                a2 = __hadd2(a2, v.h2[2]);
                a3 = __hadd2(a3, v.h2[3]);
            }
        }
        // half e of the dwordx4 is (within-pass) channel 16*e + l4:
        // tile stride 136 floats -> <=2-way bank aliasing (free).
        float2 f0 = __half22float2(a0);
        float2 f1 = __half22float2(a1);
        float2 f2 = __half22float2(a2);
        float2 f3 = __half22float2(a3);
        float* tw = &tile[w * 136 + l4];
        tw[0]   = f0.x; tw[16]  = f0.y;
        tw[32]  = f1.x; tw[48]  = f1.y;
        tw[64]  = f2.x; tw[80]  = f2.y;
        tw[96]  = f3.x; tw[112] = f3.y;
    }
    __syncthreads();

    // ---- store phase: thread = (c_local, w-half); 32 contiguous w = 128 B
    // per thread, regular cached stores (coalesce into full lines in L2).
    {
        int c    = tid & 127;
        int part = tid >> 7;
        float bv = bias[pass * 128 + c];
        float* obase = out + ((((size_t)b * COUT + pass * 128 + c) * TT + t) * HH + h) * WW
                           + part * 32;
#pragma unroll
        for (int j = 0; j < 8; ++j) {
            int w0 = part * 32 + j * 4;
            float4 v;
            v.x = tile[(w0 + 0) * 136 + c] + bv;
            v.y = tile[(w0 + 1) * 136 + c] + bv;
            v.z = tile[(w0 + 2) * 136 + c] + bv;
            v.w = tile[(w0 + 3) * 136 + c] + bv;
            *reinterpret_cast<float4*>(obase + j * 4) = v;
        }
    }
}

// ---------------------------------------------------------------------------
// Fallback (only if workspace is too small for the half table): direct fp32
// gather from the original layout. Slow but correct.
// ---------------------------------------------------------------------------
__global__ __launch_bounds__(256) void conv_direct(const int* __restrict__ idx,
                                                   const float* __restrict__ wgt,
                                                   const float* __restrict__ bias,
                                                   float* __restrict__ out) {
    int bid = blockIdx.x;                 // b*65536 + t*4096 + h*64 + w
    int w = bid & 63;
    int h = (bid >> 6) & 63;
    int t = (bid >> 12) & 15;
    int b = bid >> 16;
    int c = threadIdx.x;
    float acc = bias[c];
#pragma unroll
    for (int dt = 0; dt < 3; ++dt)
#pragma unroll
        for (int dh = 0; dh < 3; ++dh)
#pragma unroll
            for (int dw = 0; dw < 3; ++dw) {
                int ts = t + dt - 2; if (ts < 0) ts = 0;
                int hs = h + dh - 1; if (hs < 0) hs = 0; if (hs > 63) hs = 63;
                int ws = w + dw - 1; if (ws < 0) ws = 0; if (ws > 63) ws = 63;
                int n = idx[(((b * TT + ts) * HH) + hs) * WW + ws];
                acc += wgt[((size_t)(c * NCLS + n)) * 27 + (dt * 9 + dh * 3 + dw)];
            }
    out[((((size_t)b * COUT + c) * TT + t) * HH + h) * WW + w] = acc;
}

extern "C" void kernel_launch(void* const* d_in, const int* in_sizes, int n_in,
                              void* d_out, int out_size, void* d_ws, size_t ws_size,
                              hipStream_t stream) {
    const int*   indices = (const int*)d_in[0];
    const float* weight  = (const float*)d_in[1];
    const float* bias    = (const float*)d_in[2];
    float*       out     = (float*)d_out;

    if (ws_size >= TABLE_BYTES) {
        __half* tbl = (__half*)d_ws;
        repack_kernel<<<256, 256, 0, stream>>>(weight, tbl);
        conv_kernel<<<2 * BB * TT * HH, 256, 0, stream>>>(indices, tbl, bias, out);
    } else {
        conv_direct<<<BB * TT * HH * WW, 256, 0, stream>>>(indices, weight, bias, out);
    }
}

// Round 5
// 446.688 us; speedup vs baseline: 2.2081x; 1.0072x over previous
//
#include <hip/hip_runtime.h>
#include <hip/hip_fp16.h>

// Problem constants
#define NCLS 512
#define COUT 256
#define BB 4
#define TT 16
#define HH 64
#define WW 64

static constexpr size_t TABLE_ELEMS = 27ull * NCLS * COUT;   // half elements
static constexpr size_t TABLE_BYTES = TABLE_ELEMS * sizeof(__half);

// ---------------------------------------------------------------------------
// Kernel 1: repack weight (C=256, N=512, 27) fp32 -> table[27][512][256] half.
// Column j of a row holds original channel  c(j) = (j>>7)*128 + perm(j&127)
// (pass-half in bit 7; within-pass perm so a lane's dwordx4 in kernel 2 holds
// channels {l4, 16+l4, ..., 112+l4} -> conflict-free LDS transpose).
// ---------------------------------------------------------------------------
#define RST 109   // LDS row stride (floats), odd -> spread banks

__global__ __launch_bounds__(256) void repack_kernel(const float* __restrict__ w,
                                                     __half* __restrict__ tbl) {
    __shared__ float s[128 * RST];        // [c_local][n*27+k], 55.8 KB

    int bid  = blockIdx.x;                // 0..255
    int pass = bid >> 7;                  // 0/1: channel half
    int n0   = (bid & 127) << 2;          // 4 consecutive n
    int tid  = threadIdx.x;

    // ---- read: c_local r owns 108 contiguous floats (4n x 27k), 2 threads/run
    {
        int r  = tid >> 1;                // 0..127
        int l2 = tid & 1;
        int cg = pass * 128 + r;          // global channel
        const float* src = w + ((size_t)cg * NCLS + n0) * 27;
#pragma unroll
        for (int i = 0; i < 54; ++i) {
            int f = l2 + (i << 1);        // 0..107
            s[r * RST + f] = src[f];
        }
    }
    __syncthreads();

    // ---- write: dword d = k*256 + tid covers (k, n = tid>>6, pd = tid&63);
    // halves (2pd, 2pd+1) hold channels c0, c0+16 with c0 = 32*(pd&3)+(pd>>2).
    unsigned int* tb32 = reinterpret_cast<unsigned int*>(tbl);
    int n  = tid >> 6;                    // 0..3
    int pd = tid & 63;                    // 0..63
    int c0 = ((pd & 3) << 5) + (pd >> 2);
    int q0 = n * 27;
#pragma unroll
    for (int k = 0; k < 27; ++k) {
        float a = s[c0 * RST + q0 + k];
        float b = s[(c0 + 16) * RST + q0 + k];
        __half2 hv = __floats2half2_rn(a, b);
        tb32[((size_t)k * NCLS + n0 + n) * 128 + pass * 64 + pd] =
            *reinterpret_cast<unsigned int*>(&hv);
    }
}

// ---------------------------------------------------------------------------
// Kernel 2: main gather-accumulate, 2-pass channel split pinned to XCD halves.
// 8192 blocks; round-robin block->XCD dispatch puts pass 0 (channels 0-127)
// on XCDs 0-3 and pass 1 on XCDs 4-7. Per-XCD table working set = 3.5 MB ->
// L2-resident (verified: FETCH 830 MB -> 35 MB in r3).
// This round: occupancy 4 -> 8 blocks/CU. tile now stages only 32 w (17.4 KB,
// total LDS ~19.8 KB); wave w-assignment made phase-contiguous
// (w = pr*16 + wave*4 + quad) so each 32-w half is stored right after its two
// compute phases. 32 waves/CU doubles loads-in-flight to cover L2 latency.
// ---------------------------------------------------------------------------
__global__ __launch_bounds__(256, 6) void conv_kernel(const int* __restrict__ idx,
                                                      const __half* __restrict__ tbl,
                                                      const float* __restrict__ bias,
                                                      float* __restrict__ out) {
    __shared__ int soff[3 * 3 * 66];      // per-tap-row byte offsets (n << 9)
    __shared__ float tile[32 * 136];      // [w32][c_local], padded stride, 17.4 KB

    int bx   = blockIdx.x;                // 0..8191
    int pass = (bx >> 2) & 1;             // XCD half -> channel half
    int pos  = ((bx & 3) << 10) | (bx >> 3);   // bijective -> 0..4095
    int h = pos & 63;
    int t = (pos >> 6) & 15;
    int b = pos >> 10;
    int tid = threadIdx.x;

    // ---- stage clamped row byte-offsets for the (3 dt)x(3 dh)x(66 w) window
    for (int e = tid; e < 594; e += 256) {
        int tt = e / 198;
        int r  = e - tt * 198;
        int hh = r / 66;
        int ww = r - hh * 66;
        int ts = t + tt - 2; if (ts < 0) ts = 0;                 // edge pad (2,0)
        int hs = h + hh - 1; if (hs < 0) hs = 0; if (hs > 63) hs = 63;
        int ws = ww - 1;     if (ws < 0) ws = 0; if (ws > 63) ws = 63;
        int n = idx[(((b * TT + ts) * HH) + hs) * WW + ws];
        soff[e] = n << 9;                                        // n * 512 bytes
    }
    __syncthreads();

    int lane = tid & 63;
    int wave = tid >> 6;
    int quad = lane >> 4;                 // which w of the 4-group
    int l4   = lane & 15;                 // 16 B column slot within half-row
    const char* tb = (const char*)tbl + pass * 256 + l4 * 16;

    // store-phase constants (thread = (c_local, w-half))
    int cs  = tid & 127;
    int sub = tid >> 7;
    float bv = bias[pass * 128 + cs];
    float* obase = out + ((((size_t)b * COUT + pass * 128 + cs) * TT + t) * HH + h) * WW;

#pragma unroll
    for (int hp = 0; hp < 2; ++hp) {      // two 32-w halves
#pragma unroll
        for (int pr2 = 0; pr2 < 2; ++pr2) {
            int prg = (hp << 1) | pr2;                  // global phase 0..3
            int w   = (prg << 4) + (wave << 2) + quad;  // unique 0..63
            int w16 = (pr2 << 4) + (wave << 2) + quad;  // slot in tile 0..31
            __half2 a0 = __float2half2_rn(0.0f);
            __half2 a1 = a0, a2 = a0, a3 = a0;
#pragma unroll
            for (int g = 0; g < 3; ++g) {               // 3 groups of 9 taps
                int no[9];
#pragma unroll
                for (int i = 0; i < 9; ++i) {
                    int kt = g * 3 + i / 3;             // tap row (dt*3+dh)
                    int dw = i % 3;
                    no[i] = soff[kt * 66 + w + dw];
                }
                uint4 ld[9];
#pragma unroll
                for (int i = 0; i < 9; ++i) {
                    int k = g * 9 + i;                  // tap 0..26
                    ld[i] = *reinterpret_cast<const uint4*>(tb + (no[i] + k * 262144));
                }
#pragma unroll
                for (int i = 0; i < 9; ++i) {
                    union { uint4 u; __half2 h2[4]; } v; v.u = ld[i];
                    a0 = __hadd2(a0, v.h2[0]);
                    a1 = __hadd2(a1, v.h2[1]);
                    a2 = __hadd2(a2, v.h2[2]);
                    a3 = __hadd2(a3, v.h2[3]);
                }
            }
            // half e of the dwordx4 is (within-pass) channel 16*e + l4:
            // tile stride 136 -> <=2-way bank aliasing (free).
            float2 f0 = __half22float2(a0);
            float2 f1 = __half22float2(a1);
            float2 f2 = __half22float2(a2);
            float2 f3 = __half22float2(a3);
            float* tw = &tile[w16 * 136 + l4];
            tw[0]   = f0.x; tw[16]  = f0.y;
            tw[32]  = f1.x; tw[48]  = f1.y;
            tw[64]  = f2.x; tw[80]  = f2.y;
            tw[96]  = f3.x; tw[112] = f3.y;
        }
        __syncthreads();

        // ---- store 32 w: thread writes 16 contiguous w = 64 B (full sector)
        {
            float* ob = obase + (hp << 5) + (sub << 4);
#pragma unroll
            for (int q = 0; q < 4; ++q) {
                int w0 = (sub << 4) + (q << 2);
                float4 v;
                v.x = tile[(w0 + 0) * 136 + cs] + bv;
                v.y = tile[(w0 + 1) * 136 + cs] + bv;
                v.z = tile[(w0 + 2) * 136 + cs] + bv;
                v.w = tile[(w0 + 3) * 136 + cs] + bv;
                *reinterpret_cast<float4*>(ob + (q << 2)) = v;
            }
        }
        __syncthreads();
    }
}

// ---------------------------------------------------------------------------
// Fallback (only if workspace is too small for the half table): direct fp32
// gather from the original layout. Slow but correct.
// ---------------------------------------------------------------------------
__global__ __launch_bounds__(256) void conv_direct(const int* __restrict__ idx,
                                                   const float* __restrict__ wgt,
                                                   const float* __restrict__ bias,
                                                   float* __restrict__ out) {
    int bid = blockIdx.x;                 // b*65536 + t*4096 + h*64 + w
    int w = bid & 63;
    int h = (bid >> 6) & 63;
    int t = (bid >> 12) & 15;
    int b = bid >> 16;
    int c = threadIdx.x;
    float acc = bias[c];
#pragma unroll
    for (int dt = 0; dt < 3; ++dt)
#pragma unroll
        for (int dh = 0; dh < 3; ++dh)
#pragma unroll
            for (int dw = 0; dw < 3; ++dw) {
                int ts = t + dt - 2; if (ts < 0) ts = 0;
                int hs = h + dh - 1; if (hs < 0) hs = 0; if (hs > 63) hs = 63;
                int ws = w + dw - 1; if (ws < 0) ws = 0; if (ws > 63) ws = 63;
                int n = idx[(((b * TT + ts) * HH) + hs) * WW + ws];
                acc += wgt[((size_t)(c * NCLS + n)) * 27 + (dt * 9 + dh * 3 + dw)];
            }
    out[((((size_t)b * COUT + c) * TT + t) * HH + h) * WW + w] = acc;
}

extern "C" void kernel_launch(void* const* d_in, const int* in_sizes, int n_in,
                              void* d_out, int out_size, void* d_ws, size_t ws_size,
                              hipStream_t stream) {
    const int*   indices = (const int*)d_in[0];
    const float* weight  = (const float*)d_in[1];
    const float* bias    = (const float*)d_in[2];
    float*       out     = (float*)d_out;

    if (ws_size >= TABLE_BYTES) {
        __half* tbl = (__half*)d_ws;
        repack_kernel<<<256, 256, 0, stream>>>(weight, tbl);
        conv_kernel<<<2 * BB * TT * HH, 256, 0, stream>>>(indices, tbl, bias, out);
    } else {
        conv_direct<<<BB * TT * HH * WW, 256, 0, stream>>>(indices, weight, bias, out);
    }
}

// Round 6
// 444.896 us; speedup vs baseline: 2.2170x; 1.0040x over previous
//
#include <hip/hip_runtime.h>
#include <hip/hip_fp16.h>

// Problem constants
#define NCLS 512
#define COUT 256
#define BB 4
#define TT 16
#define HH 64
#define WW 64

typedef unsigned int vuint4 __attribute__((ext_vector_type(4)));

static constexpr size_t TABLE_ELEMS = 27ull * NCLS * COUT;   // half elements
static constexpr size_t TABLE_BYTES = TABLE_ELEMS * sizeof(__half);

// ---------------------------------------------------------------------------
// Kernel 1: repack weight (C=256, N=512, 27) fp32 -> table[27][512][256] half.
// Column j of a row holds original channel  c(j) = (j>>7)*128 + perm(j&127)
// (pass-half in bit 7; within-pass perm so a lane's dwordx4 in kernel 2 holds
// channels {l4, 16+l4, ..., 112+l4} -> conflict-free LDS transpose).
// ---------------------------------------------------------------------------
#define RST 109   // LDS row stride (floats), odd -> spread banks

__global__ __launch_bounds__(256) void repack_kernel(const float* __restrict__ w,
                                                     __half* __restrict__ tbl) {
    __shared__ float s[128 * RST];        // [c_local][n*27+k], 55.8 KB

    int bid  = blockIdx.x;                // 0..255
    int pass = bid >> 7;                  // 0/1: channel half
    int n0   = (bid & 127) << 2;          // 4 consecutive n
    int tid  = threadIdx.x;

    // ---- read: c_local r owns 108 contiguous floats (4n x 27k), 2 threads/run
    {
        int r  = tid >> 1;                // 0..127
        int l2 = tid & 1;
        int cg = pass * 128 + r;          // global channel
        const float* src = w + ((size_t)cg * NCLS + n0) * 27;
#pragma unroll
        for (int i = 0; i < 54; ++i) {
            int f = l2 + (i << 1);        // 0..107
            s[r * RST + f] = src[f];
        }
    }
    __syncthreads();

    // ---- write: dword d = k*256 + tid covers (k, n = tid>>6, pd = tid&63);
    // halves (2pd, 2pd+1) hold channels c0, c0+16 with c0 = 32*(pd&3)+(pd>>2).
    unsigned int* tb32 = reinterpret_cast<unsigned int*>(tbl);
    int n  = tid >> 6;                    // 0..3
    int pd = tid & 63;                    // 0..63
    int c0 = ((pd & 3) << 5) + (pd >> 2);
    int q0 = n * 27;
#pragma unroll
    for (int k = 0; k < 27; ++k) {
        float a = s[c0 * RST + q0 + k];
        float b = s[(c0 + 16) * RST + q0 + k];
        __half2 hv = __floats2half2_rn(a, b);
        tb32[((size_t)k * NCLS + n0 + n) * 128 + pass * 64 + pd] =
            *reinterpret_cast<unsigned int*>(&hv);
    }
}

// ---------------------------------------------------------------------------
// Kernel 2: main gather-accumulate, 2-pass channel split pinned to XCD halves
// (table L2-resident per XCD: FETCH 830 MB -> 140 MB, verified r3/r5).
// This round: table loads switch to inline-asm global_load_dwordx4 **sc0**
// (L1-bypass, L2-coherent) to escape the per-CU L1-MSHR cap (r5 evidence:
// occupancy 38->65% changed nothing; per-CU gather rate stuck at ~27 B/cy).
// Loads issue in 9-deep groups, 2 groups in flight, counted s_waitcnt
// vmcnt(9) between groups (never drain to 0 mid-phase), sched_barrier(0)
// after each wait (rule #18: register-only hadd2 would hoist past the wait).
// ---------------------------------------------------------------------------
#define ISSUE_GROUP(gg, par)                                               \
    _Pragma("unroll")                                                      \
    for (int i = 0; i < 9; ++i) {                                          \
        int kt = (gg) * 3 + i / 3;          /* tap row dt*3+dh */          \
        int dw = i - (i / 3) * 3;                                          \
        int k  = (gg) * 9 + i;              /* tap 0..26 */                \
        const char* ga = tb + (soff[kt * 66 + w + dw] + k * 262144);       \
        asm volatile("global_load_dwordx4 %0, %1, off sc0"                 \
                     : "=v"(ld[par][i]) : "v"(ga));                        \
    }

#define ACCUM(par)                                                         \
    _Pragma("unroll")                                                      \
    for (int i = 0; i < 9; ++i) {                                          \
        union { vuint4 u; __half2 h2[4]; } v;                              \
        v.u = ld[par][i];                                                  \
        a0 = __hadd2(a0, v.h2[0]);                                         \
        a1 = __hadd2(a1, v.h2[1]);                                         \
        a2 = __hadd2(a2, v.h2[2]);                                         \
        a3 = __hadd2(a3, v.h2[3]);                                         \
    }

__global__ __launch_bounds__(256, 4) void conv_kernel(const int* __restrict__ idx,
                                                      const __half* __restrict__ tbl,
                                                      const float* __restrict__ bias,
                                                      float* __restrict__ out) {
    __shared__ int soff[3 * 3 * 66];      // per-tap-row byte offsets (n << 9)
    __shared__ float tile[32 * 136];      // [w32][c_local], padded stride, 17.4 KB

    int bx   = blockIdx.x;                // 0..8191
    int pass = (bx >> 2) & 1;             // XCD half -> channel half
    int pos  = ((bx & 3) << 10) | (bx >> 3);   // bijective -> 0..4095
    int h = pos & 63;
    int t = (pos >> 6) & 15;
    int b = pos >> 10;
    int tid = threadIdx.x;

    // ---- stage clamped row byte-offsets for the (3 dt)x(3 dh)x(66 w) window
    for (int e = tid; e < 594; e += 256) {
        int tt = e / 198;
        int r  = e - tt * 198;
        int hh = r / 66;
        int ww = r - hh * 66;
        int ts = t + tt - 2; if (ts < 0) ts = 0;                 // edge pad (2,0)
        int hs = h + hh - 1; if (hs < 0) hs = 0; if (hs > 63) hs = 63;
        int ws = ww - 1;     if (ws < 0) ws = 0; if (ws > 63) ws = 63;
        int n = idx[(((b * TT + ts) * HH) + hs) * WW + ws];
        soff[e] = n << 9;                                        // n * 512 bytes
    }
    __syncthreads();

    int lane = tid & 63;
    int wave = tid >> 6;
    int quad = lane >> 4;                 // which w of the 4-group
    int l4   = lane & 15;                 // 16 B column slot within half-row
    const char* tb = (const char*)tbl + pass * 256 + l4 * 16;

    // store-phase constants (thread = (c_local, w-half))
    int cs  = tid & 127;
    int sub = tid >> 7;
    float bv = bias[pass * 128 + cs];
    float* obase = out + ((((size_t)b * COUT + pass * 128 + cs) * TT + t) * HH + h) * WW;

#pragma unroll
    for (int hp = 0; hp < 2; ++hp) {      // two 32-w halves
#pragma unroll
        for (int pr2 = 0; pr2 < 2; ++pr2) {
            int prg = (hp << 1) | pr2;                  // global phase 0..3
            int w   = (prg << 4) + (wave << 2) + quad;  // unique 0..63
            int w16 = (pr2 << 4) + (wave << 2) + quad;  // slot in tile 0..31
            __half2 a0 = __float2half2_rn(0.0f);
            __half2 a1 = a0, a2 = a0, a3 = a0;

            vuint4 ld[2][9];
            ISSUE_GROUP(0, 0);
            ISSUE_GROUP(1, 1);
            asm volatile("s_waitcnt vmcnt(9)" ::: "memory");   // group 0 arrived
            __builtin_amdgcn_sched_barrier(0);
            ACCUM(0);
            ISSUE_GROUP(2, 0);                                 // reuse slot 0
            asm volatile("s_waitcnt vmcnt(9)" ::: "memory");   // group 1 arrived
            __builtin_amdgcn_sched_barrier(0);
            ACCUM(1);
            asm volatile("s_waitcnt vmcnt(0)" ::: "memory");   // group 2 arrived
            __builtin_amdgcn_sched_barrier(0);
            ACCUM(0);

            // half e of the dwordx4 is (within-pass) channel 16*e + l4:
            // tile stride 136 -> bank-minimal (<=2 lanes/bank).
            float2 f0 = __half22float2(a0);
            float2 f1 = __half22float2(a1);
            float2 f2 = __half22float2(a2);
            float2 f3 = __half22float2(a3);
            float* tw = &tile[w16 * 136 + l4];
            tw[0]   = f0.x; tw[16]  = f0.y;
            tw[32]  = f1.x; tw[48]  = f1.y;
            tw[64]  = f2.x; tw[80]  = f2.y;
            tw[96]  = f3.x; tw[112] = f3.y;
        }
        __syncthreads();

        // ---- store 32 w: thread writes 16 contiguous w = 64 B (full sector)
        {
            float* ob = obase + (hp << 5) + (sub << 4);
#pragma unroll
            for (int q = 0; q < 4; ++q) {
                int w0 = (sub << 4) + (q << 2);
                float4 v;
                v.x = tile[(w0 + 0) * 136 + cs] + bv;
                v.y = tile[(w0 + 1) * 136 + cs] + bv;
                v.z = tile[(w0 + 2) * 136 + cs] + bv;
                v.w = tile[(w0 + 3) * 136 + cs] + bv;
                *reinterpret_cast<float4*>(ob + (q << 2)) = v;
            }
        }
        __syncthreads();
    }
}

// ---------------------------------------------------------------------------
// Fallback (only if workspace is too small for the half table): direct fp32
// gather from the original layout. Slow but correct.
// ---------------------------------------------------------------------------
__global__ __launch_bounds__(256) void conv_direct(const int* __restrict__ idx,
                                                   const float* __restrict__ wgt,
                                                   const float* __restrict__ bias,
                                                   float* __restrict__ out) {
    int bid = blockIdx.x;                 // b*65536 + t*4096 + h*64 + w
    int w = bid & 63;
    int h = (bid >> 6) & 63;
    int t = (bid >> 12) & 15;
    int b = bid >> 16;
    int c = threadIdx.x;
    float acc = bias[c];
#pragma unroll
    for (int dt = 0; dt < 3; ++dt)
#pragma unroll
        for (int dh = 0; dh < 3; ++dh)
#pragma unroll
            for (int dw = 0; dw < 3; ++dw) {
                int ts = t + dt - 2; if (ts < 0) ts = 0;
                int hs = h + dh - 1; if (hs < 0) hs = 0; if (hs > 63) hs = 63;
                int ws = w + dw - 1; if (ws < 0) ws = 0; if (ws > 63) ws = 63;
                int n = idx[(((b * TT + ts) * HH) + hs) * WW + ws];
                acc += wgt[((size_t)(c * NCLS + n)) * 27 + (dt * 9 + dh * 3 + dw)];
            }
    out[((((size_t)b * COUT + c) * TT + t) * HH + h) * WW + w] = acc;
}

extern "C" void kernel_launch(void* const* d_in, const int* in_sizes, int n_in,
                              void* d_out, int out_size, void* d_ws, size_t ws_size,
                              hipStream_t stream) {
    const int*   indices = (const int*)d_in[0];
    const float* weight  = (const float*)d_in[1];
    const float* bias    = (const float*)d_in[2];
    float*       out     = (float*)d_out;

    if (ws_size >= TABLE_BYTES) {
        __half* tbl = (__half*)d_ws;
        repack_kernel<<<256, 256, 0, stream>>>(weight, tbl);
        conv_kernel<<<2 * BB * TT * HH, 256, 0, stream>>>(indices, tbl, bias, out);
    } else {
        conv_direct<<<BB * TT * HH * WW, 256, 0, stream>>>(indices, weight, bias, out);
    }
}